// Round 7
// baseline (310.545 us; speedup 1.0000x reference)
//
#include <hip/hip_runtime.h>
#include <hip/hip_cooperative_groups.h>

namespace cg = cooperative_groups;

// DCNv2 fused v7: cooperative persistent kernel (grid=512, guaranteed
// co-resident), error-checked launch with fallback to the proven v5
// two-dispatch path. Phase 1: x->xt[n][hw][c] bf16 transpose + weight recast
// to swizzled wt slots (jobs striped over 512 blocks). grid.sync(). Phase 2:
// 1152 px-tiles via atomic work-steal; per tile: meta, tap-outer loop with
// half-tap (64o, 16KB) weight slabs double-buffered via global_load_lds;
// B-fragment built once per tap, reused by both o-halves. MFMA 16x16x32 bf16.

#define NI 8
#define CI 128
#define HI 96
#define WI 96
#define CO 128
#define K2 9
#define P_TOT 9216
#define TP 64
#define NT_TILES 1152                               // NI * P_TOT / TP
#define GRID_COOP 512
#define XT_ELEMS ((size_t)NI * P_TOT * CI)          // 9,437,184 bf16
#define WT_ELEMS ((size_t)K2 * CO * CI)             // 147,456 bf16
#define WS_NEED ((XT_ELEMS + WT_ELEMS) * 2 + 64)
#define CPAD 40                                     // no-ws fallback only

// smem carve (bytes) for coop kernel
#define SM_MIDX 0
#define SM_MW   4608
#define SM_W0   13824
#define SM_W1   30208
#define SM_TILE 46592
#define SM_SIZE 46608

typedef short short8 __attribute__((ext_vector_type(8)));
typedef float f32x4 __attribute__((ext_vector_type(4)));

static __device__ __forceinline__ ushort bf16_rne(float x) {
    unsigned u = __float_as_uint(x);
    u = (u + 0x7FFF + ((u >> 16) & 1)) >> 16;
    return (ushort)u;
}
static __device__ __forceinline__ unsigned pack_bf2(float a, float b) {
    return (unsigned)bf16_rne(a) | ((unsigned)bf16_rne(b) << 16);
}
static __device__ __forceinline__ float bflo(unsigned u) { return __uint_as_float(u << 16); }
static __device__ __forceinline__ float bfhi(unsigned u) { return __uint_as_float(u & 0xFFFF0000u); }

union U4S8 { uint4 u; short8 s; };

static __device__ __forceinline__ void gll16(const ushort* g, ushort* l) {
    __builtin_amdgcn_global_load_lds(
        (const __attribute__((address_space(1))) unsigned int*)g,
        (__attribute__((address_space(3))) unsigned int*)l, 16, 0, 0);
}

// ---- meta computation shared by all kernels ----
static __device__ __forceinline__ void compute_meta(
    const float* __restrict__ offset, const float* __restrict__ mask,
    int n, int p0, int item, uint2* s_midx, float4* s_mw)
{
    int k = item / TP;
    int i = item % TP;
    int p  = p0 + i;
    int ph = p / WI;
    int pw = p % WI;
    float offy = offset[((size_t)n * (2 * K2) + 2 * k    ) * P_TOT + p];
    float offx = offset[((size_t)n * (2 * K2) + 2 * k + 1) * P_TOT + p];
    float m    = mask  [((size_t)n * K2 + k) * P_TOT + p];
    int ky = k / 3, kx = k % 3;
    float py = (float)(ph - 1 + ky) + offy;
    float px = (float)(pw - 1 + kx) + offx;
    float y0f = floorf(py), x0f = floorf(px);
    float wy = py - y0f, wx = px - x0f;
    int y0 = (int)y0f, x0 = (int)x0f;
    int y1 = y0 + 1,  x1 = x0 + 1;
    bool vy0 = (y0 >= 0) && (y0 < HI);
    bool vy1 = (y1 >= 0) && (y1 < HI);
    bool vx0 = (x0 >= 0) && (x0 < WI);
    bool vx1 = (x1 >= 0) && (x1 < WI);
    unsigned i00 = (vy0 && vx0) ? (unsigned)(y0 * WI + x0) : 0u;
    unsigned i01 = (vy0 && vx1) ? (unsigned)(y0 * WI + x1) : 0u;
    unsigned i10 = (vy1 && vx0) ? (unsigned)(y1 * WI + x0) : 0u;
    unsigned i11 = (vy1 && vx1) ? (unsigned)(y1 * WI + x1) : 0u;
    float w00 = (vy0 && vx0) ? (1.f - wy) * (1.f - wx) * m : 0.f;
    float w01 = (vy0 && vx1) ? (1.f - wy) * wx          * m : 0.f;
    float w10 = (vy1 && vx0) ? wy * (1.f - wx)          * m : 0.f;
    float w11 = (vy1 && vx1) ? wy * wx                  * m : 0.f;
    s_midx[item] = make_uint2(i00 | (i01 << 16), i10 | (i11 << 16));
    s_mw[item]   = make_float4(w00, w01, w10, w11);
}

// ==================== cooperative single-dispatch kernel ====================
__global__ __launch_bounds__(256, 3)
void dcn_coop_kernel(const float* __restrict__ x,
                     const float* __restrict__ offset,
                     const float* __restrict__ mask,
                     const float* __restrict__ weight,
                     const float* __restrict__ bias,
                     float* __restrict__ out,
                     ushort* __restrict__ xt,
                     ushort* __restrict__ wt,
                     unsigned* __restrict__ cnt)
{
    __shared__ __align__(16) char smem[SM_SIZE];
    uint2*  s_midx = (uint2*)(smem + SM_MIDX);
    float4* s_mw   = (float4*)(smem + SM_MW);
    ushort* s_w0   = (ushort*)(smem + SM_W0);
    ushort* s_w1   = (ushort*)(smem + SM_W1);
    unsigned* s_tile = (unsigned*)(smem + SM_TILE);

    const int tid = threadIdx.x;
    const int bid = blockIdx.x;

    // ======== phase 1: build xt and wt (jobs striped over 512 blocks) ======
    for (int job = bid; job < 648; job += GRID_COOP) {
        if (job < 576) {
            ushort (*tileT)[260] = (ushort(*)[260])smem;
            const int n = job / 72, rr = job % 72;
            const int cblk = rr & 1, hw0 = (rr >> 1) * 256;
            __syncthreads();        // protect tileT from previous job readers
            #pragma unroll
            for (int it = 0; it < 16; ++it) {
                int item = it * 256 + tid;          // < 4096
                int c = item >> 6, q = item & 63;
                float4 f = *(const float4*)(x + ((size_t)(n * CI + cblk * 64 + c)) * P_TOT
                                            + hw0 + q * 4);
                ushort tmp[4] = {bf16_rne(f.x), bf16_rne(f.y), bf16_rne(f.z), bf16_rne(f.w)};
                *(uint2*)&tileT[c][q * 4] = *(uint2*)tmp;
            }
            __syncthreads();
            #pragma unroll
            for (int it = 0; it < 16; ++it) {
                int item = it * 256 + tid;          // < 4096
                int row = item >> 4, seg = item & 15;
                ushort tmp[4];
                #pragma unroll
                for (int i = 0; i < 4; ++i) tmp[i] = tileT[seg * 4 + i][row];
                *(uint2*)(xt + ((size_t)n * P_TOT + hw0 + row) * CI + cblk * 64 + seg * 4)
                    = *(uint2*)tmp;
            }
        } else {
            // wt slot s = k*2048 + o*16 + csw ; cs = csw ^ (o&7)
            int s = (job - 576) * 256 + tid;        // < 18432
            int k   = s >> 11;
            int r2  = s & 2047;
            int o   = r2 >> 4;
            int csw = r2 & 15;
            int cs  = csw ^ (o & 7);
            const float* src = weight + (size_t)o * (CI * K2) + cs * 8 * K2 + k;
            ushort tmp[8];
            #pragma unroll
            for (int j = 0; j < 8; ++j) tmp[j] = bf16_rne(src[j * K2]);
            *(uint4*)&wt[(size_t)s * 8] = *(uint4*)tmp;
        }
    }
    if (bid == 300 && tid == 0) atomicExch(cnt, 0u);

    cg::this_grid().sync();

    // ======== phase 2: persistent tile loop ========
    const int wave = tid >> 6;
    const int lane = tid & 63;
    const int l15  = lane & 15;
    const int quad = lane >> 4;

    auto stage = [&](int k, int half, ushort* dst) {
        const ushort* g = wt + ((size_t)(k * 2048 + half * 1024 + wave * 256)) * 8;
        ushort* l = dst + (size_t)(wave * 256) * 8;
        #pragma unroll
        for (int i = 0; i < 4; ++i)
            gll16(g + (size_t)(i * 64 + lane) * 8, l + i * 64 * 8);
    };

    for (;;) {
        if (tid == 0) *s_tile = atomicAdd(cnt, 1u);
        __syncthreads();            // broadcast t; prev-tile readers done
        unsigned t = *s_tile;
        if (t >= NT_TILES) break;
        const int n  = (int)(t & 7);
        const int p0 = (int)(t >> 3) * TP;

        stage(0, 0, s_w0);
        stage(0, 1, s_w1);

        for (int it = 0; it < 3; ++it) {
            int item = it * 256 + tid;
            if (item < K2 * TP) compute_meta(offset, mask, n, p0, item, s_midx, s_mw);
        }
        __syncthreads();            // meta visible; tap0 slabs landed

        f32x4 acc[8];
        #pragma unroll
        for (int a = 0; a < 8; ++a) acc[a] = (f32x4){0.f, 0.f, 0.f, 0.f};

        const ushort* xb = xt + (size_t)n * (P_TOT * CI) + quad * 8;

        for (int k = 0; k < K2; ++k) {
            uint2  mi = s_midx[k * TP + wave * 16 + l15];
            float4 mw = s_mw[k * TP + wave * 16 + l15];
            const ushort* c00 = xb + (size_t)(mi.x & 0xFFFF) * CI;
            const ushort* c01 = xb + (size_t)(mi.x >> 16)    * CI;
            const ushort* c10 = xb + (size_t)(mi.y & 0xFFFF) * CI;
            const ushort* c11 = xb + (size_t)(mi.y >> 16)    * CI;

            short8 bfr[4];
            {
                uint4 ra[4], rb[4];
                ra[0] = *(const uint4*)(c00);      ra[1] = *(const uint4*)(c01);
                ra[2] = *(const uint4*)(c10);      ra[3] = *(const uint4*)(c11);
                rb[0] = *(const uint4*)(c00 + 32); rb[1] = *(const uint4*)(c01 + 32);
                rb[2] = *(const uint4*)(c10 + 32); rb[3] = *(const uint4*)(c11 + 32);
                #pragma unroll
                for (int cb = 0; cb < 4; ++cb) {
                    uint4 r0 = (cb & 1) ? rb[0] : ra[0];
                    uint4 r1 = (cb & 1) ? rb[1] : ra[1];
                    uint4 r2 = (cb & 1) ? rb[2] : ra[2];
                    uint4 r3 = (cb & 1) ? rb[3] : ra[3];
                    float v0 = mw.x * bflo(r0.x) + mw.y * bflo(r1.x) + mw.z * bflo(r2.x) + mw.w * bflo(r3.x);
                    float v1 = mw.x * bfhi(r0.x) + mw.y * bfhi(r1.x) + mw.z * bfhi(r2.x) + mw.w * bfhi(r3.x);
                    float v2 = mw.x * bflo(r0.y) + mw.y * bflo(r1.y) + mw.z * bflo(r2.y) + mw.w * bflo(r3.y);
                    float v3 = mw.x * bfhi(r0.y) + mw.y * bfhi(r1.y) + mw.z * bfhi(r2.y) + mw.w * bfhi(r3.y);
                    float v4 = mw.x * bflo(r0.z) + mw.y * bflo(r1.z) + mw.z * bflo(r2.z) + mw.w * bflo(r3.z);
                    float v5 = mw.x * bfhi(r0.z) + mw.y * bfhi(r1.z) + mw.z * bfhi(r2.z) + mw.w * bfhi(r3.z);
                    float v6 = mw.x * bflo(r0.w) + mw.y * bflo(r1.w) + mw.z * bflo(r2.w) + mw.w * bflo(r3.w);
                    float v7 = mw.x * bfhi(r0.w) + mw.y * bfhi(r1.w) + mw.z * bfhi(r2.w) + mw.w * bfhi(r3.w);
                    if (cb == 0) {
                        ra[0] = *(const uint4*)(c00 + 64); ra[1] = *(const uint4*)(c01 + 64);
                        ra[2] = *(const uint4*)(c10 + 64); ra[3] = *(const uint4*)(c11 + 64);
                    } else if (cb == 1) {
                        rb[0] = *(const uint4*)(c00 + 96); rb[1] = *(const uint4*)(c01 + 96);
                        rb[2] = *(const uint4*)(c10 + 96); rb[3] = *(const uint4*)(c11 + 96);
                    }
                    U4S8 cvt;
                    cvt.u.x = pack_bf2(v0, v1);
                    cvt.u.y = pack_bf2(v2, v3);
                    cvt.u.z = pack_bf2(v4, v5);
                    cvt.u.w = pack_bf2(v6, v7);
                    bfr[cb] = cvt.s;
                }
            }

            #pragma unroll
            for (int cb = 0; cb < 4; ++cb)
                #pragma unroll
                for (int ot = 0; ot < 4; ++ot) {
                    int ol = ot * 16 + l15;
                    short8 afr = *(const short8*)&s_w0[ol * 128 + (((cb * 4 + quad) ^ (ol & 7)) * 8)];
                    acc[ot] = __builtin_amdgcn_mfma_f32_16x16x32_bf16(afr, bfr[cb], acc[ot], 0, 0, 0);
                }
            __syncthreads();                    // lo reads done; hi slab landed
            if (k < 8) stage(k + 1, 0, s_w0);

            #pragma unroll
            for (int cb = 0; cb < 4; ++cb)
                #pragma unroll
                for (int ot = 0; ot < 4; ++ot) {
                    int ol = ot * 16 + l15;
                    short8 afr = *(const short8*)&s_w1[ol * 128 + (((cb * 4 + quad) ^ (ol & 7)) * 8)];
                    acc[4 + ot] = __builtin_amdgcn_mfma_f32_16x16x32_bf16(afr, bfr[cb], acc[4 + ot], 0, 0, 0);
                }
            __syncthreads();                    // hi reads done; next lo landed
            if (k < 8) stage(k + 1, 1, s_w1);
        }

        #pragma unroll
        for (int ot = 0; ot < 8; ++ot) {
            #pragma unroll
            for (int r = 0; r < 4; ++r) {
                int o = ot * 16 + quad * 4 + r;
                int p = p0 + wave * 16 + l15;
                out[((size_t)n * CO + o) * P_TOT + p] = acc[ot][r] + bias[o];
            }
        }
    }
}

// ==================== v5 two-dispatch path (proven, fallback) ===============
__global__ __launch_bounds__(256)
void pre_kernel(const float* __restrict__ x, const float* __restrict__ w,
                ushort* __restrict__ xt, ushort* __restrict__ wt) {
    const int bid = blockIdx.x;
    const int tid = threadIdx.x;
    if (bid < 576) {
        __shared__ ushort t[256][68];
        const int n = bid / 72, rr = bid % 72;
        const int cblk = rr & 1, hw0 = (rr >> 1) * 256;
        #pragma unroll
        for (int j = 0; j < 16; ++j) {
            int item = j * 256 + tid;
            int c = item >> 6, q = item & 63;
            float4 f = *(const float4*)(x + ((size_t)(n * CI + cblk * 64 + c)) * P_TOT
                                        + hw0 + q * 4);
            t[q * 4 + 0][c] = bf16_rne(f.x);
            t[q * 4 + 1][c] = bf16_rne(f.y);
            t[q * 4 + 2][c] = bf16_rne(f.z);
            t[q * 4 + 3][c] = bf16_rne(f.w);
        }
        __syncthreads();
        #pragma unroll
        for (int j = 0; j < 16; ++j) {
            int item = j * 256 + tid;
            int row = item >> 4, seg = item & 15;
            uint2 v = *(const uint2*)&t[row][seg * 4];
            *(uint2*)(xt + ((size_t)n * P_TOT + hw0 + row) * CI + cblk * 64 + seg * 4) = v;
        }
    } else {
        int s = (bid - 576) * 256 + tid;
        int k   = s >> 11;
        int r2  = s & 2047;
        int o   = r2 >> 4;
        int csw = r2 & 15;
        int cs  = csw ^ (o & 7);
        const float* src = w + (size_t)o * (CI * K2) + cs * 8 * K2 + k;
        ushort tmp[8];
        #pragma unroll
        for (int j = 0; j < 8; ++j) tmp[j] = bf16_rne(src[j * K2]);
        *(uint4*)&wt[(size_t)s * 8] = *(uint4*)tmp;
    }
}

__global__ __launch_bounds__(256, 2)
void dcn_mfma4_kernel(const ushort* __restrict__ xt,
                      const ushort* __restrict__ wt,
                      const float* __restrict__ offset,
                      const float* __restrict__ mask,
                      const float* __restrict__ bias,
                      float* __restrict__ out)
{
    __shared__ uint2  s_midx[K2 * TP];
    __shared__ float4 s_mw[K2 * TP];
    __shared__ ushort s_w[2][CO * CI];

    const int tid  = threadIdx.x;
    const int bid  = blockIdx.x;
    const int n    = bid & 7;
    const int p0   = (bid >> 3) * TP;
    const int wave = tid >> 6;
    const int lane = tid & 63;
    const int l15  = lane & 15;
    const int quad = lane >> 4;

    auto stage = [&](int k, int buf) {
        const ushort* g = wt + ((size_t)k * 2048 + wave * 512) * 8;
        ushort* l = &s_w[buf][wave * 512 * 8];
        #pragma unroll
        for (int i = 0; i < 8; ++i)
            gll16(g + (size_t)(i * 64 + lane) * 8, l + i * 64 * 8);
    };

    stage(0, 0);

    for (int it = 0; it < 3; ++it) {
        int item = it * 256 + tid;
        if (item < K2 * TP) compute_meta(offset, mask, n, p0, item, s_midx, s_mw);
    }
    __syncthreads();

    f32x4 acc[8];
    #pragma unroll
    for (int a = 0; a < 8; ++a) acc[a] = (f32x4){0.f, 0.f, 0.f, 0.f};

    const ushort* xb = xt + (size_t)n * (P_TOT * CI) + quad * 8;

    for (int k = 0; k < K2; ++k) {
        const int buf = k & 1;
        if (k < 8) stage(k + 1, buf ^ 1);

        uint2  mi = s_midx[k * TP + wave * 16 + l15];
        float4 mw = s_mw[k * TP + wave * 16 + l15];
        const ushort* c00 = xb + (size_t)(mi.x & 0xFFFF) * CI;
        const ushort* c01 = xb + (size_t)(mi.x >> 16)    * CI;
        const ushort* c10 = xb + (size_t)(mi.y & 0xFFFF) * CI;
        const ushort* c11 = xb + (size_t)(mi.y >> 16)    * CI;

        uint4 ra[4], rb[4];
        ra[0] = *(const uint4*)(c00);      ra[1] = *(const uint4*)(c01);
        ra[2] = *(const uint4*)(c10);      ra[3] = *(const uint4*)(c11);
        rb[0] = *(const uint4*)(c00 + 32); rb[1] = *(const uint4*)(c01 + 32);
        rb[2] = *(const uint4*)(c10 + 32); rb[3] = *(const uint4*)(c11 + 32);

        #pragma unroll
        for (int cb = 0; cb < 4; ++cb) {
            uint4 r0 = (cb & 1) ? rb[0] : ra[0];
            uint4 r1 = (cb & 1) ? rb[1] : ra[1];
            uint4 r2 = (cb & 1) ? rb[2] : ra[2];
            uint4 r3 = (cb & 1) ? rb[3] : ra[3];
            float v0 = mw.x * bflo(r0.x) + mw.y * bflo(r1.x) + mw.z * bflo(r2.x) + mw.w * bflo(r3.x);
            float v1 = mw.x * bfhi(r0.x) + mw.y * bfhi(r1.x) + mw.z * bfhi(r2.x) + mw.w * bfhi(r3.x);
            float v2 = mw.x * bflo(r0.y) + mw.y * bflo(r1.y) + mw.z * bflo(r2.y) + mw.w * bflo(r3.y);
            float v3 = mw.x * bfhi(r0.y) + mw.y * bfhi(r1.y) + mw.z * bfhi(r2.y) + mw.w * bfhi(r3.y);
            float v4 = mw.x * bflo(r0.z) + mw.y * bflo(r1.z) + mw.z * bflo(r2.z) + mw.w * bflo(r3.z);
            float v5 = mw.x * bfhi(r0.z) + mw.y * bfhi(r1.z) + mw.z * bfhi(r2.z) + mw.w * bfhi(r3.z);
            float v6 = mw.x * bflo(r0.w) + mw.y * bflo(r1.w) + mw.z * bflo(r2.w) + mw.w * bflo(r3.w);
            float v7 = mw.x * bfhi(r0.w) + mw.y * bfhi(r1.w) + mw.z * bfhi(r2.w) + mw.w * bfhi(r3.w);
            if (cb == 0) {
                ra[0] = *(const uint4*)(c00 + 64); ra[1] = *(const uint4*)(c01 + 64);
                ra[2] = *(const uint4*)(c10 + 64); ra[3] = *(const uint4*)(c11 + 64);
            } else if (cb == 1) {
                rb[0] = *(const uint4*)(c00 + 96); rb[1] = *(const uint4*)(c01 + 96);
                rb[2] = *(const uint4*)(c10 + 96); rb[3] = *(const uint4*)(c11 + 96);
            }
            U4S8 cvt;
            cvt.u.x = pack_bf2(v0, v1);
            cvt.u.y = pack_bf2(v2, v3);
            cvt.u.z = pack_bf2(v4, v5);
            cvt.u.w = pack_bf2(v6, v7);
            short8 bfr = cvt.s;
            #pragma unroll
            for (int ot = 0; ot < 8; ++ot) {
                int o = ot * 16 + l15;
                short8 afr = *(const short8*)&s_w[buf][o * CI + (((cb * 4 + quad) ^ (o & 7)) * 8)];
                acc[ot] = __builtin_amdgcn_mfma_f32_16x16x32_bf16(afr, bfr, acc[ot], 0, 0, 0);
            }
        }
        __syncthreads();
    }

    #pragma unroll
    for (int ot = 0; ot < 8; ++ot) {
        #pragma unroll
        for (int r = 0; r < 4; ++r) {
            int o = ot * 16 + quad * 4 + r;
            int p = p0 + wave * 16 + l15;
            out[((size_t)n * CO + o) * P_TOT + p] = acc[ot][r] + bias[o];
        }
    }
}

// ---------------- fallback (no workspace): round-2 structure ----------------
__global__ __launch_bounds__(256, 3)
void dcn_fallback_kernel(const float* __restrict__ x,
                         const float* __restrict__ offset,
                         const float* __restrict__ mask,
                         const float* __restrict__ weight,
                         const float* __restrict__ bias,
                         float* __restrict__ out)
{
    __shared__ uint2  s_midx[K2 * TP];
    __shared__ float4 s_mw[K2 * TP];
    __shared__ ushort s_v[TP * CPAD];
    __shared__ ushort s_w[CO * CPAD];

    const int tid  = threadIdx.x;
    const int bid  = blockIdx.x;
    const int n    = bid & 7;
    const int p0   = (bid >> 3) * TP;

    for (int it = 0; it < 3; ++it) {
        int item = it * 256 + tid;
        if (item < K2 * TP) compute_meta(offset, mask, n, p0, item, s_midx, s_mw);
    }
    __syncthreads();

    const int wave = tid >> 6;
    const int lane = tid & 63;
    const int l15  = lane & 15;
    const int quad = lane >> 4;
    const int o_base = (wave >> 1) * 64;
    const int p_base = (wave & 1) * 32;
    const int gp = tid & 63;
    const int cg2 = wave;

    f32x4 acc[4][2];
    #pragma unroll
    for (int a = 0; a < 4; ++a)
        #pragma unroll
        for (int b = 0; b < 2; ++b) acc[a][b] = (f32x4){0.f, 0.f, 0.f, 0.f};

    for (int cb = 0; cb < 4; ++cb) {
        for (int k = 0; k < K2; ++k) {
            {
                uint2  mi = s_midx[k * TP + gp];
                float4 mw = s_mw[k * TP + gp];
                int i00 = mi.x & 0xFFFF, i01 = mi.x >> 16;
                int i10 = mi.y & 0xFFFF, i11 = mi.y >> 16;
                const float* xb = x + ((size_t)(n * CI + cb * 32 + cg2 * 8)) * (HI * WI);
                float v[8];
                #pragma unroll
                for (int j = 0; j < 8; ++j) {
                    const float* xp = xb + (size_t)j * (HI * WI);
                    v[j] = mw.x * xp[i00] + mw.y * xp[i01]
                         + mw.z * xp[i10] + mw.w * xp[i11];
                }
                uint4 pk;
                pk.x = pack_bf2(v[0], v[1]);
                pk.y = pack_bf2(v[2], v[3]);
                pk.z = pack_bf2(v[4], v[5]);
                pk.w = pack_bf2(v[6], v[7]);
                *(uint4*)&s_v[gp * CPAD + cg2 * 8] = pk;
            }
            {
                int o = tid >> 1, half = tid & 1;
                const float* wsrc = weight + (size_t)o * (CI * K2)
                                  + (cb * 32 + half * 16) * K2 + k;
                ushort tmp[16];
                #pragma unroll
                for (int i = 0; i < 16; ++i) tmp[i] = bf16_rne(wsrc[i * K2]);
                *(uint4*)&s_w[o * CPAD + half * 16]     = *(uint4*)&tmp[0];
                *(uint4*)&s_w[o * CPAD + half * 16 + 8] = *(uint4*)&tmp[8];
            }
            __syncthreads();
            short8 afr[4], bfr[2];
            #pragma unroll
            for (int ot = 0; ot < 4; ++ot)
                afr[ot] = *(const short8*)&s_w[(o_base + ot * 16 + l15) * CPAD + quad * 8];
            #pragma unroll
            for (int pt = 0; pt < 2; ++pt)
                bfr[pt] = *(const short8*)&s_v[(p_base + pt * 16 + l15) * CPAD + quad * 8];
            #pragma unroll
            for (int ot = 0; ot < 4; ++ot)
                #pragma unroll
                for (int pt = 0; pt < 2; ++pt)
                    acc[ot][pt] = __builtin_amdgcn_mfma_f32_16x16x32_bf16(
                        afr[ot], bfr[pt], acc[ot][pt], 0, 0, 0);
            __syncthreads();
        }
    }

    #pragma unroll
    for (int ot = 0; ot < 4; ++ot)
        #pragma unroll
        for (int r = 0; r < 4; ++r) {
            int o = o_base + ot * 16 + quad * 4 + r;
            float b = bias[o];
            #pragma unroll
            for (int pt = 0; pt < 2; ++pt) {
                int p = p0 + p_base + pt * 16 + l15;
                out[((size_t)n * CO + o) * P_TOT + p] = acc[ot][pt][r] + b;
            }
        }
}

extern "C" void kernel_launch(void* const* d_in, const int* in_sizes, int n_in,
                              void* d_out, int out_size, void* d_ws, size_t ws_size,
                              hipStream_t stream) {
    const float* x      = (const float*)d_in[0];
    const float* offset = (const float*)d_in[1];
    const float* mask   = (const float*)d_in[2];
    const float* weight = (const float*)d_in[3];
    const float* bias   = (const float*)d_in[4];
    float* out = (float*)d_out;

    if (ws_size >= WS_NEED) {
        ushort* xt = (ushort*)d_ws;
        ushort* wt = xt + XT_ELEMS;
        unsigned* cnt = (unsigned*)(wt + WT_ELEMS);
        void* args[] = {(void*)&x, (void*)&offset, (void*)&mask, (void*)&weight,
                        (void*)&bias, (void*)&out, (void*)&xt, (void*)&wt, (void*)&cnt};
        hipError_t err = hipLaunchCooperativeKernel((const void*)dcn_coop_kernel,
                                                    dim3(GRID_COOP), dim3(256),
                                                    args, 0, stream);
        if (err == hipSuccess) return;
        // cooperative launch rejected -> proven two-dispatch path
        pre_kernel<<<dim3(576 + 72), dim3(256), 0, stream>>>(x, weight, xt, wt);
        dcn_mfma4_kernel<<<dim3(NT_TILES), dim3(256), 0, stream>>>(
            xt, wt, offset, mask, bias, out);
    } else {
        dcn_fallback_kernel<<<dim3(NT_TILES), dim3(256), 0, stream>>>(
            x, offset, mask, weight, bias, out);
    }
}

// Round 8
// 214.231 us; speedup vs baseline: 1.4496x; 1.4496x over previous
//
#include <hip/hip_runtime.h>

// DCNv2 fused v8: two-dispatch (pre + main). Main: 512-thread blocks,
// TP=128 px/tile, grid 576 with n=bid&7 (XCD-pinned -> xt[n] L2-resident).
// Tap-outer loop; half-tap (64o, 16KB) weight slabs double-buffered via
// global_load_lds from pre-swizzled wt; B-frag register gather from
// xt[n][hw][c] bf16; MFMA f32_16x16x32_bf16. 16 waves/CU.

#define NI 8
#define CI 128
#define HI 96
#define WI 96
#define CO 128
#define K2 9
#define P_TOT 9216
#define TP 64                                       // fallback tile
#define TP2 128                                     // main tile
#define NT_TILES 1152                               // fallback grid
#define GRID2 576                                   // main grid (8n x 72)
#define XT_ELEMS ((size_t)NI * P_TOT * CI)          // 9,437,184 bf16
#define WT_ELEMS ((size_t)K2 * CO * CI)             // 147,456 bf16
#define WS_NEED ((XT_ELEMS + WT_ELEMS) * 2 + 64)
#define CPAD 40                                     // no-ws fallback only

typedef short short8 __attribute__((ext_vector_type(8)));
typedef float f32x4 __attribute__((ext_vector_type(4)));

static __device__ __forceinline__ ushort bf16_rne(float x) {
    unsigned u = __float_as_uint(x);
    u = (u + 0x7FFF + ((u >> 16) & 1)) >> 16;
    return (ushort)u;
}
static __device__ __forceinline__ unsigned pack_bf2(float a, float b) {
    return (unsigned)bf16_rne(a) | ((unsigned)bf16_rne(b) << 16);
}
static __device__ __forceinline__ float bflo(unsigned u) { return __uint_as_float(u << 16); }
static __device__ __forceinline__ float bfhi(unsigned u) { return __uint_as_float(u & 0xFFFF0000u); }

union U4S8 { uint4 u; short8 s; };

static __device__ __forceinline__ void gll16(const ushort* g, ushort* l) {
    __builtin_amdgcn_global_load_lds(
        (const __attribute__((address_space(1))) unsigned int*)g,
        (__attribute__((address_space(3))) unsigned int*)l, 16, 0, 0);
}

// ---- meta computation (tp = pixels per tile) ----
static __device__ __forceinline__ void compute_meta(
    const float* __restrict__ offset, const float* __restrict__ mask,
    int n, int p0, int item, int tp, uint2* s_midx, float4* s_mw)
{
    int k = item / tp;
    int i = item % tp;
    int p  = p0 + i;
    int ph = p / WI;
    int pw = p % WI;
    float offy = offset[((size_t)n * (2 * K2) + 2 * k    ) * P_TOT + p];
    float offx = offset[((size_t)n * (2 * K2) + 2 * k + 1) * P_TOT + p];
    float m    = mask  [((size_t)n * K2 + k) * P_TOT + p];
    int ky = k / 3, kx = k % 3;
    float py = (float)(ph - 1 + ky) + offy;
    float px = (float)(pw - 1 + kx) + offx;
    float y0f = floorf(py), x0f = floorf(px);
    float wy = py - y0f, wx = px - x0f;
    int y0 = (int)y0f, x0 = (int)x0f;
    int y1 = y0 + 1,  x1 = x0 + 1;
    bool vy0 = (y0 >= 0) && (y0 < HI);
    bool vy1 = (y1 >= 0) && (y1 < HI);
    bool vx0 = (x0 >= 0) && (x0 < WI);
    bool vx1 = (x1 >= 0) && (x1 < WI);
    unsigned i00 = (vy0 && vx0) ? (unsigned)(y0 * WI + x0) : 0u;
    unsigned i01 = (vy0 && vx1) ? (unsigned)(y0 * WI + x1) : 0u;
    unsigned i10 = (vy1 && vx0) ? (unsigned)(y1 * WI + x0) : 0u;
    unsigned i11 = (vy1 && vx1) ? (unsigned)(y1 * WI + x1) : 0u;
    float w00 = (vy0 && vx0) ? (1.f - wy) * (1.f - wx) * m : 0.f;
    float w01 = (vy0 && vx1) ? (1.f - wy) * wx          * m : 0.f;
    float w10 = (vy1 && vx0) ? wy * (1.f - wx)          * m : 0.f;
    float w11 = (vy1 && vx1) ? wy * wx                  * m : 0.f;
    s_midx[item] = make_uint2(i00 | (i01 << 16), i10 | (i11 << 16));
    s_mw[item]   = make_float4(w00, w01, w10, w11);
}

// ==================== pre-kernel (proven): xt + swizzled wt =================
__global__ __launch_bounds__(256)
void pre_kernel(const float* __restrict__ x, const float* __restrict__ w,
                ushort* __restrict__ xt, ushort* __restrict__ wt) {
    const int bid = blockIdx.x;
    const int tid = threadIdx.x;
    if (bid < 576) {
        __shared__ ushort t[256][68];
        const int n = bid / 72, rr = bid % 72;
        const int cblk = rr & 1, hw0 = (rr >> 1) * 256;
        #pragma unroll
        for (int j = 0; j < 16; ++j) {
            int item = j * 256 + tid;
            int c = item >> 6, q = item & 63;
            float4 f = *(const float4*)(x + ((size_t)(n * CI + cblk * 64 + c)) * P_TOT
                                        + hw0 + q * 4);
            t[q * 4 + 0][c] = bf16_rne(f.x);
            t[q * 4 + 1][c] = bf16_rne(f.y);
            t[q * 4 + 2][c] = bf16_rne(f.z);
            t[q * 4 + 3][c] = bf16_rne(f.w);
        }
        __syncthreads();
        #pragma unroll
        for (int j = 0; j < 16; ++j) {
            int item = j * 256 + tid;
            int row = item >> 4, seg = item & 15;
            uint2 v = *(const uint2*)&t[row][seg * 4];
            *(uint2*)(xt + ((size_t)n * P_TOT + hw0 + row) * CI + cblk * 64 + seg * 4) = v;
        }
    } else {
        // wt slot s = k*2048 + o*16 + csw ; cs = csw ^ (o&7)
        int s = (bid - 576) * 256 + tid;            // < 18432
        int k   = s >> 11;
        int r2  = s & 2047;
        int o   = r2 >> 4;
        int csw = r2 & 15;
        int cs  = csw ^ (o & 7);
        const float* src = w + (size_t)o * (CI * K2) + cs * 8 * K2 + k;
        ushort tmp[8];
        #pragma unroll
        for (int j = 0; j < 8; ++j) tmp[j] = bf16_rne(src[j * K2]);
        *(uint4*)&wt[(size_t)s * 8] = *(uint4*)tmp;
    }
}

// ==================== main kernel: 512 threads, TP2=128 px ==================
__global__ __launch_bounds__(512, 4)
void dcn_mfma5_kernel(const ushort* __restrict__ xt,
                      const ushort* __restrict__ wt,
                      const float* __restrict__ offset,
                      const float* __restrict__ mask,
                      const float* __restrict__ bias,
                      float* __restrict__ out)
{
    __shared__ uint2  s_midx[K2 * TP2];     // 9216 B
    __shared__ float4 s_mw[K2 * TP2];       // 18432 B
    __shared__ ushort s_w0[64 * CI];        // 16 KB lo-half slab (swizzled)
    __shared__ ushort s_w1[64 * CI];        // 16 KB hi-half slab

    const int tid  = threadIdx.x;
    const int bid  = blockIdx.x;
    const int n    = bid & 7;               // XCD-pinned image
    const int p0   = (bid >> 3) * TP2;
    const int wave = tid >> 6;              // 0..7
    const int lane = tid & 63;
    const int l15  = lane & 15;
    const int quad = lane >> 4;

    // async-stage one half-tap slab (1024 slots of 16B; 2 issues/wave)
    auto stage = [&](int k, int half, ushort* dst) {
        const ushort* g = wt + ((size_t)(k * 2048 + half * 1024 + wave * 128)) * 8;
        ushort* l = dst + (size_t)(wave * 128) * 8;
        #pragma unroll
        for (int i = 0; i < 2; ++i)
            gll16(g + (size_t)(i * 64 + lane) * 8, l + i * 64 * 8);
    };

    stage(0, 0, s_w0);          // tap0 slabs in flight under meta phase
    stage(0, 1, s_w1);

    // ---- meta phase: 1152 items over 512 threads ----
    for (int it = 0; it < 3; ++it) {
        int item = it * 512 + tid;
        if (item < K2 * TP2) compute_meta(offset, mask, n, p0, item, TP2, s_midx, s_mw);
    }
    __syncthreads();            // meta visible; tap0 slabs landed (vmcnt drain)

    f32x4 acc[8];
    #pragma unroll
    for (int a = 0; a < 8; ++a) acc[a] = (f32x4){0.f, 0.f, 0.f, 0.f};

    const ushort* xb = xt + (size_t)n * (P_TOT * CI) + quad * 8;

    for (int k = 0; k < K2; ++k) {
        // ---- gather: build B-frags (4 cb) once per tap ----
        uint2  mi = s_midx[k * TP2 + wave * 16 + l15];
        float4 mw = s_mw[k * TP2 + wave * 16 + l15];
        const ushort* c00 = xb + (size_t)(mi.x & 0xFFFF) * CI;
        const ushort* c01 = xb + (size_t)(mi.x >> 16)    * CI;
        const ushort* c10 = xb + (size_t)(mi.y & 0xFFFF) * CI;
        const ushort* c11 = xb + (size_t)(mi.y >> 16)    * CI;

        short8 bfr[4];
        {
            uint4 ra[4], rb[4];
            ra[0] = *(const uint4*)(c00);      ra[1] = *(const uint4*)(c01);
            ra[2] = *(const uint4*)(c10);      ra[3] = *(const uint4*)(c11);
            rb[0] = *(const uint4*)(c00 + 32); rb[1] = *(const uint4*)(c01 + 32);
            rb[2] = *(const uint4*)(c10 + 32); rb[3] = *(const uint4*)(c11 + 32);
            #pragma unroll
            for (int cb = 0; cb < 4; ++cb) {
                uint4 r0 = (cb & 1) ? rb[0] : ra[0];
                uint4 r1 = (cb & 1) ? rb[1] : ra[1];
                uint4 r2 = (cb & 1) ? rb[2] : ra[2];
                uint4 r3 = (cb & 1) ? rb[3] : ra[3];
                float v0 = mw.x * bflo(r0.x) + mw.y * bflo(r1.x) + mw.z * bflo(r2.x) + mw.w * bflo(r3.x);
                float v1 = mw.x * bfhi(r0.x) + mw.y * bfhi(r1.x) + mw.z * bfhi(r2.x) + mw.w * bfhi(r3.x);
                float v2 = mw.x * bflo(r0.y) + mw.y * bflo(r1.y) + mw.z * bflo(r2.y) + mw.w * bflo(r3.y);
                float v3 = mw.x * bfhi(r0.y) + mw.y * bfhi(r1.y) + mw.z * bfhi(r2.y) + mw.w * bfhi(r3.y);
                float v4 = mw.x * bflo(r0.z) + mw.y * bflo(r1.z) + mw.z * bflo(r2.z) + mw.w * bflo(r3.z);
                float v5 = mw.x * bfhi(r0.z) + mw.y * bfhi(r1.z) + mw.z * bfhi(r2.z) + mw.w * bfhi(r3.z);
                float v6 = mw.x * bflo(r0.w) + mw.y * bflo(r1.w) + mw.z * bflo(r2.w) + mw.w * bflo(r3.w);
                float v7 = mw.x * bfhi(r0.w) + mw.y * bfhi(r1.w) + mw.z * bfhi(r2.w) + mw.w * bfhi(r3.w);
                if (cb == 0) {
                    ra[0] = *(const uint4*)(c00 + 64); ra[1] = *(const uint4*)(c01 + 64);
                    ra[2] = *(const uint4*)(c10 + 64); ra[3] = *(const uint4*)(c11 + 64);
                } else if (cb == 1) {
                    rb[0] = *(const uint4*)(c00 + 96); rb[1] = *(const uint4*)(c01 + 96);
                    rb[2] = *(const uint4*)(c10 + 96); rb[3] = *(const uint4*)(c11 + 96);
                }
                U4S8 cvt;
                cvt.u.x = pack_bf2(v0, v1);
                cvt.u.y = pack_bf2(v2, v3);
                cvt.u.z = pack_bf2(v4, v5);
                cvt.u.w = pack_bf2(v6, v7);
                bfr[cb] = cvt.s;
            }
        }

        // ---- lo half (o 0..63) ----
        #pragma unroll
        for (int cb = 0; cb < 4; ++cb)
            #pragma unroll
            for (int ot = 0; ot < 4; ++ot) {
                int ol = ot * 16 + l15;
                short8 afr = *(const short8*)&s_w0[ol * 128 + (((cb * 4 + quad) ^ (ol & 7)) * 8)];
                acc[ot] = __builtin_amdgcn_mfma_f32_16x16x32_bf16(afr, bfr[cb], acc[ot], 0, 0, 0);
            }
        __syncthreads();                    // lo reads done; hi slab landed
        if (k < 8) stage(k + 1, 0, s_w0);

        // ---- hi half (o 64..127) ----
        #pragma unroll
        for (int cb = 0; cb < 4; ++cb)
            #pragma unroll
            for (int ot = 0; ot < 4; ++ot) {
                int ol = ot * 16 + l15;
                short8 afr = *(const short8*)&s_w1[ol * 128 + (((cb * 4 + quad) ^ (ol & 7)) * 8)];
                acc[4 + ot] = __builtin_amdgcn_mfma_f32_16x16x32_bf16(afr, bfr[cb], acc[4 + ot], 0, 0, 0);
            }
        __syncthreads();                    // hi reads done; next lo landed
        if (k < 8) stage(k + 1, 1, s_w1);
    }

    // ---- epilogue ----
    #pragma unroll
    for (int ot = 0; ot < 8; ++ot) {
        #pragma unroll
        for (int r = 0; r < 4; ++r) {
            int o = ot * 16 + quad * 4 + r;
            int p = p0 + wave * 16 + l15;
            out[((size_t)n * CO + o) * P_TOT + p] = acc[ot][r] + bias[o];
        }
    }
}

// ---------------- fallback (no workspace): round-2 structure ----------------
__global__ __launch_bounds__(256, 3)
void dcn_fallback_kernel(const float* __restrict__ x,
                         const float* __restrict__ offset,
                         const float* __restrict__ mask,
                         const float* __restrict__ weight,
                         const float* __restrict__ bias,
                         float* __restrict__ out)
{
    __shared__ uint2  s_midx[K2 * TP];
    __shared__ float4 s_mw[K2 * TP];
    __shared__ ushort s_v[TP * CPAD];
    __shared__ ushort s_w[CO * CPAD];

    const int tid  = threadIdx.x;
    const int bid  = blockIdx.x;
    const int n    = bid & 7;
    const int p0   = (bid >> 3) * TP;

    for (int it = 0; it < 3; ++it) {
        int item = it * 256 + tid;
        if (item < K2 * TP) compute_meta(offset, mask, n, p0, item, TP, s_midx, s_mw);
    }
    __syncthreads();

    const int wave = tid >> 6;
    const int lane = tid & 63;
    const int l15  = lane & 15;
    const int quad = lane >> 4;
    const int o_base = (wave >> 1) * 64;
    const int p_base = (wave & 1) * 32;
    const int gp = tid & 63;
    const int cg2 = wave;

    f32x4 acc[4][2];
    #pragma unroll
    for (int a = 0; a < 4; ++a)
        #pragma unroll
        for (int b = 0; b < 2; ++b) acc[a][b] = (f32x4){0.f, 0.f, 0.f, 0.f};

    for (int cb = 0; cb < 4; ++cb) {
        for (int k = 0; k < K2; ++k) {
            {
                uint2  mi = s_midx[k * TP + gp];
                float4 mw = s_mw[k * TP + gp];
                int i00 = mi.x & 0xFFFF, i01 = mi.x >> 16;
                int i10 = mi.y & 0xFFFF, i11 = mi.y >> 16;
                const float* xb = x + ((size_t)(n * CI + cb * 32 + cg2 * 8)) * (HI * WI);
                float v[8];
                #pragma unroll
                for (int j = 0; j < 8; ++j) {
                    const float* xp = xb + (size_t)j * (HI * WI);
                    v[j] = mw.x * xp[i00] + mw.y * xp[i01]
                         + mw.z * xp[i10] + mw.w * xp[i11];
                }
                uint4 pk;
                pk.x = pack_bf2(v[0], v[1]);
                pk.y = pack_bf2(v[2], v[3]);
                pk.z = pack_bf2(v[4], v[5]);
                pk.w = pack_bf2(v[6], v[7]);
                *(uint4*)&s_v[gp * CPAD + cg2 * 8] = pk;
            }
            {
                int o = tid >> 1, half = tid & 1;
                const float* wsrc = weight + (size_t)o * (CI * K2)
                                  + (cb * 32 + half * 16) * K2 + k;
                ushort tmp[16];
                #pragma unroll
                for (int i = 0; i < 16; ++i) tmp[i] = bf16_rne(wsrc[i * K2]);
                *(uint4*)&s_w[o * CPAD + half * 16]     = *(uint4*)&tmp[0];
                *(uint4*)&s_w[o * CPAD + half * 16 + 8] = *(uint4*)&tmp[8];
            }
            __syncthreads();
            short8 afr[4], bfr[2];
            #pragma unroll
            for (int ot = 0; ot < 4; ++ot)
                afr[ot] = *(const short8*)&s_w[(o_base + ot * 16 + l15) * CPAD + quad * 8];
            #pragma unroll
            for (int pt = 0; pt < 2; ++pt)
                bfr[pt] = *(const short8*)&s_v[(p_base + pt * 16 + l15) * CPAD + quad * 8];
            #pragma unroll
            for (int ot = 0; ot < 4; ++ot)
                #pragma unroll
                for (int pt = 0; pt < 2; ++pt)
                    acc[ot][pt] = __builtin_amdgcn_mfma_f32_16x16x32_bf16(
                        afr[ot], bfr[pt], acc[ot][pt], 0, 0, 0);
            __syncthreads();
        }
    }

    #pragma unroll
    for (int ot = 0; ot < 4; ++ot)
        #pragma unroll
        for (int r = 0; r < 4; ++r) {
            int o = o_base + ot * 16 + quad * 4 + r;
            float b = bias[o];
            #pragma unroll
            for (int pt = 0; pt < 2; ++pt) {
                int p = p0 + p_base + pt * 16 + l15;
                out[((size_t)n * CO + o) * P_TOT + p] = acc[ot][pt][r] + b;
            }
        }
}

extern "C" void kernel_launch(void* const* d_in, const int* in_sizes, int n_in,
                              void* d_out, int out_size, void* d_ws, size_t ws_size,
                              hipStream_t stream) {
    const float* x      = (const float*)d_in[0];
    const float* offset = (const float*)d_in[1];
    const float* mask   = (const float*)d_in[2];
    const float* weight = (const float*)d_in[3];
    const float* bias   = (const float*)d_in[4];
    float* out = (float*)d_out;

    if (ws_size >= WS_NEED) {
        ushort* xt = (ushort*)d_ws;
        ushort* wt = xt + XT_ELEMS;
        pre_kernel<<<dim3(576 + 72), dim3(256), 0, stream>>>(x, weight, xt, wt);
        dcn_mfma5_kernel<<<dim3(GRID2), dim3(512), 0, stream>>>(
            xt, wt, offset, mask, bias, out);
    } else {
        dcn_fallback_kernel<<<dim3(NT_TILES), dim3(256), 0, stream>>>(
            x, offset, mask, weight, bias, out);
    }
}